// Round 1
// baseline (1229.061 us; speedup 1.0000x reference)
//
#include <hip/hip_runtime.h>
#include <hip/hip_bf16.h>

#define BB 256
#define TT 64
#define XD 512
#define CCG 256
#define DINk 768
#define HH 1024
#define G4 4096
#define NTAG 512

typedef float f32x4 __attribute__((ext_vector_type(4)));
typedef short s16x8 __attribute__((ext_vector_type(8)));

// ---- workspace layout (bytes) ----
#define WS_HBUF  0ull
#define WS_HS    (WS_HBUF + 2ull*BB*HH*2)            // h double buffer: 1 MiB
#define WS_XBASE (WS_HS + (size_t)TT*BB*HH*2)        // hs: 32 MiB
#define WS_EPROJ (WS_XBASE + (size_t)BB*G4*4)        // xbase: 4 MiB
#define WS_WIH   (WS_EPROJ + (size_t)NTAG*G4*4)      // embproj: 8 MiB
#define WS_WOUT  (WS_WIH + (size_t)G4*DINk*2)        // W_ih bf16: 6 MiB
#define WS_XBF   (WS_WOUT + (size_t)NTAG*HH*2)       // W_out bf16: 1 MiB
#define WS_EMBBF (WS_XBF + (size_t)BB*XD*2)          // x bf16
#define WS_CNT   (WS_EMBBF + (size_t)NTAG*CCG*2)     // barrier counters (256 ints)
#define WS_ACC   (WS_CNT + 1024)                     // nll_sum, mask_sum
#define WS_FLAG  (WS_ACC + 64)                       // mask-dtype flag

static __device__ __forceinline__ short f2bf(float f) {
  __hip_bfloat16 h = __float2bfloat16(f);
  return __builtin_bit_cast(short, h);
}

// ---- generic fp32 -> bf16 convert, 8 elems/thread ----
__global__ void k_f2bf8(const float* __restrict__ in, short* __restrict__ out, int n8) {
  int i = blockIdx.x * blockDim.x + threadIdx.x;
  if (i >= n8) return;
  size_t idx = (size_t)i * 8;
  float4 a = *(const float4*)(in + idx);
  float4 b = *(const float4*)(in + idx + 4);
  s16x8 o;
  o[0]=f2bf(a.x); o[1]=f2bf(a.y); o[2]=f2bf(a.z); o[3]=f2bf(a.w);
  o[4]=f2bf(b.x); o[5]=f2bf(b.y); o[6]=f2bf(b.z); o[7]=f2bf(b.w);
  *(s16x8*)(out + idx) = o;
}

// ---- init: h0->bf16 hbuf[0], zero counters/accumulators, detect mask dtype ----
__global__ void k_init(const float* __restrict__ h0, const int* __restrict__ mask_as_int,
                       char* __restrict__ ws) {
  int tid = blockIdx.x * blockDim.x + threadIdx.x;
  short* hb0 = (short*)(ws + WS_HBUF);
  for (int i = tid; i < BB * HH; i += gridDim.x * blockDim.x) hb0[i] = f2bf(h0[i]);
  if (blockIdx.x == 0) {
    int* cnt = (int*)(ws + WS_CNT);
    for (int i = threadIdx.x; i < 256; i += blockDim.x) cnt[i] = 0;
    // mask dtype detection: first 16384 bytes viewed as 4096 int32.
    // If mask is bool-bytes, some int32 will have high bytes set (>1).
    int v = 0;
    for (int i = threadIdx.x; i < 4096; i += blockDim.x) v |= (mask_as_int[i] & ~1);
    __shared__ int red[256];
    red[threadIdx.x] = v;
    __syncthreads();
    if (threadIdx.x == 0) {
      int a = 0;
      for (int j = 0; j < 256; j++) a |= red[j];
      ((int*)(ws + WS_FLAG))[0] = (a != 0) ? 1 : 0;
      float* acc = (float*)(ws + WS_ACC);
      acc[0] = 0.f; acc[1] = 0.f;
    }
  }
}

// ---- simple bf16 MFMA GEMM: C[M][N] = A[M][K] * Bm[N][K]^T (+bias1+bias2) ----
// grid=(M/64, N/64), block=256. No LDS; relies on L2.
__global__ __launch_bounds__(256) void k_gemm(const short* __restrict__ A, int lda,
    const short* __restrict__ Bm, int ldb, int bcol0,
    float* __restrict__ C, int ldc, int ksteps,
    const float* __restrict__ bias1, const float* __restrict__ bias2) {
  int w = threadIdx.x >> 6, l = threadIdx.x & 63;
  int lc = l & 15, lq = l >> 4;
  int arow = blockIdx.x * 64 + w * 16 + lc;
  f32x4 acc[4];
  const f32x4 z = {0.f, 0.f, 0.f, 0.f};
#pragma unroll
  for (int i = 0; i < 4; i++) acc[i] = z;
  const short* ap = A + (size_t)arow * lda + lq * 8;
  for (int kk = 0; kk < ksteps; ++kk) {
    s16x8 a = *(const s16x8*)(ap + kk * 32);
#pragma unroll
    for (int nt = 0; nt < 4; ++nt) {
      int brow = blockIdx.y * 64 + nt * 16 + lc;
      s16x8 b = *(const s16x8*)(Bm + (size_t)brow * ldb + bcol0 + kk * 32 + lq * 8);
      acc[nt] = __builtin_amdgcn_mfma_f32_16x16x32_bf16(a, b, acc[nt], 0, 0, 0);
    }
  }
#pragma unroll
  for (int nt = 0; nt < 4; ++nt) {
    int col = blockIdx.y * 64 + nt * 16 + lc;
    float badd = (bias1 ? bias1[col] : 0.f) + (bias2 ? bias2[col] : 0.f);
#pragma unroll
    for (int j = 0; j < 4; j++) {
      int r = blockIdx.x * 64 + w * 16 + lq * 4 + j;
      C[(size_t)r * ldc + col] = acc[nt][j] + badd;
    }
  }
}

// ---- persistent LSTM recurrence ----
// 256 WGs, 1/CU. Group = 64 WGs sharing 64 batch rows; each WG owns 16 hidden cols.
// W_hh slice (4 gates x 16 rows x 1024) bf16 in 128 KiB LDS, XOR-swizzled.
__global__ __launch_bounds__(256, 1) void k_lstm(const float* __restrict__ Whh,
    const int* __restrict__ atruth, const float* __restrict__ c0, char* __restrict__ ws) {
  extern __shared__ char sm[];
  const int bid = blockIdx.x;
  const int xcd = bid & 7, slot = bid >> 3;
  const int mg = xcd >> 1;              // batch group 0..3 (2 XCDs per group)
  const int hb = slot * 2 + (xcd & 1);  // hidden block 0..63
  const int tid = threadIdx.x;
  const int w = tid >> 6, l = tid & 63;
  const int lc = l & 15, lq = l >> 4;

  // stage W_hh slice -> LDS (bf16, swizzled): LDS row r=g*16+rl at r*2048, byte k ^ ((rl&7)<<4)
  {
    const int r = tid >> 2, q = tid & 3;
    const int g = r >> 4, rl = r & 15;
    const float* src = Whh + (size_t)(g * HH + hb * 16 + rl) * HH + q * 256;
    const int swz = (rl & 7) << 4;
    char* dst = sm + r * 2048;
    for (int i = 0; i < 256; i += 8) {
      float4 f0 = *(const float4*)(src + i);
      float4 f1 = *(const float4*)(src + i + 4);
      s16x8 o;
      o[0]=f2bf(f0.x); o[1]=f2bf(f0.y); o[2]=f2bf(f0.z); o[3]=f2bf(f0.w);
      o[4]=f2bf(f1.x); o[5]=f2bf(f1.y); o[6]=f2bf(f1.z); o[7]=f2bf(f1.w);
      int koff = (q * 256 + i) * 2;
      *(s16x8*)(dst + (koff ^ swz)) = o;
    }
  }

  const int mrow0 = mg * 64 + w * 16;
  const int colbase = hb * 16;
  const float* xb = (const float*)(ws + WS_XBASE);
  const float* ep = (const float*)(ws + WS_EPROJ);
  float cst[4];
  float xin[4][4];
#pragma unroll
  for (int j = 0; j < 4; j++) {
    int br = mrow0 + lq * 4 + j;
    cst[j] = c0[(size_t)br * HH + colbase + lc];
#pragma unroll
    for (int g = 0; g < 4; ++g) xin[g][j] = xb[(size_t)br * G4 + g * HH + colbase + lc];
  }
  short* hbuf0 = (short*)(ws + WS_HBUF);
  short* hs = (short*)(ws + WS_HS);
  int* cnt = (int*)(ws + WS_CNT);
  const int swzl = (lc & 7) << 4;
  __syncthreads();

  for (int t = 0; t < TT; ++t) {
    f32x4 acc[4];
#pragma unroll
    for (int j = 0; j < 4; j++) {
      int br = mrow0 + lq * 4 + j;
      int tok = (t == 0) ? 0 : atruth[br * TT + t - 1];
      const float* er = ep + (size_t)tok * G4 + colbase + lc;
      acc[0][j] = xin[0][j] + er[0];
      acc[1][j] = xin[1][j] + er[HH];
      acc[2][j] = xin[2][j] + er[2 * HH];
      acc[3][j] = xin[3][j] + er[3 * HH];
    }
    const short* arow = hbuf0 + (size_t)(t & 1) * BB * HH + (size_t)(mrow0 + lc) * HH + lq * 8;
#pragma unroll 8
    for (int kk = 0; kk < 32; ++kk) {
      s16x8 a = *(const s16x8*)(arow + kk * 32);
      const int kx = (kk * 64 + lq * 16) ^ swzl;
      const char* bp = sm + kx + lc * 2048;
      acc[0] = __builtin_amdgcn_mfma_f32_16x16x32_bf16(a, *(const s16x8*)(bp), acc[0], 0, 0, 0);
      acc[1] = __builtin_amdgcn_mfma_f32_16x16x32_bf16(a, *(const s16x8*)(bp + 16 * 2048), acc[1], 0, 0, 0);
      acc[2] = __builtin_amdgcn_mfma_f32_16x16x32_bf16(a, *(const s16x8*)(bp + 32 * 2048), acc[2], 0, 0, 0);
      acc[3] = __builtin_amdgcn_mfma_f32_16x16x32_bf16(a, *(const s16x8*)(bp + 48 * 2048), acc[3], 0, 0, 0);
    }
    short* hdst = hbuf0 + (size_t)((t + 1) & 1) * BB * HH;
#pragma unroll
    for (int j = 0; j < 4; j++) {
      float iv = 1.f / (1.f + __expf(-acc[0][j]));
      float fv = 1.f / (1.f + __expf(-acc[1][j]));
      float gv = tanhf(acc[2][j]);
      float ov = 1.f / (1.f + __expf(-acc[3][j]));
      float cv = fv * cst[j] + iv * gv;
      cst[j] = cv;
      float hv = ov * tanhf(cv);
      short h16 = f2bf(hv);
      int br = mrow0 + lq * 4 + j;
      hdst[(size_t)br * HH + colbase + lc] = h16;
      hs[((size_t)t * BB + br) * HH + colbase + lc] = h16;
    }
    __syncthreads();  // drains all waves' stores (vmcnt 0 before s_barrier)
    if (t < TT - 1) {
      if (tid == 0) {
        __builtin_amdgcn_fence(__ATOMIC_RELEASE, "agent");
        __hip_atomic_fetch_add(&cnt[mg * 64 + t], 1, __ATOMIC_RELAXED, __HIP_MEMORY_SCOPE_AGENT);
        while (__hip_atomic_load(&cnt[mg * 64 + t], __ATOMIC_RELAXED, __HIP_MEMORY_SCOPE_AGENT) < 64) {
          __builtin_amdgcn_s_sleep(1);
        }
        __builtin_amdgcn_fence(__ATOMIC_ACQUIRE, "agent");
      }
      __syncthreads();
    }
  }
}

// ---- logits + fused log-softmax + masked NLL partial sums ----
// grid=256 (16384 rows / 64), block=256. W_out k-block staged in 64 KiB LDS.
__global__ __launch_bounds__(256, 1) void k_logits(const short* __restrict__ hsb,
    const short* __restrict__ Wo, const float* __restrict__ bout,
    const int* __restrict__ atruth, const void* __restrict__ maskp,
    char* __restrict__ ws) {
  extern __shared__ char sm[];
  const int tid = threadIdx.x;
  const int w = tid >> 6, l = tid & 63;
  const int lc = l & 15, lq = l >> 4;
  const int rowbase = blockIdx.x * 64 + w * 16;
  f32x4 acc[32];
#pragma unroll
  for (int nt = 0; nt < 32; ++nt) {
    float bv = bout[nt * 16 + lc];
    f32x4 tmp = {bv, bv, bv, bv};
    acc[nt] = tmp;
  }
  const int swzl = (lc & 7) << 4;
  for (int kb = 0; kb < 16; ++kb) {
    __syncthreads();
    {
      const int r0 = tid >> 3, q = tid & 7;
#pragma unroll
      for (int i = 0; i < 16; i++) {
        int r = r0 + 32 * i;
        s16x8 v = *(const s16x8*)(Wo + (size_t)r * HH + kb * 64 + q * 8);
        *(s16x8*)(sm + r * 128 + ((q * 16) ^ ((r & 7) << 4))) = v;
      }
    }
    __syncthreads();
#pragma unroll
    for (int ks = 0; ks < 2; ++ks) {
      s16x8 a = *(const s16x8*)(hsb + (size_t)(rowbase + lc) * HH + kb * 64 + ks * 32 + lq * 8);
      const int kx = (ks * 64 + lq * 16) ^ swzl;
#pragma unroll
      for (int nt = 0; nt < 32; ++nt) {
        s16x8 b = *(const s16x8*)(sm + (nt * 16 + lc) * 128 + kx);
        acc[nt] = __builtin_amdgcn_mfma_f32_16x16x32_bf16(a, b, acc[nt], 0, 0, 0);
      }
    }
  }
  // epilogue: per-row log-softmax + target NLL
  const int bytemode = ((const int*)(ws + WS_FLAG))[0];
  const unsigned char* mb = (const unsigned char*)maskp;
  const int* mi = (const int*)maskp;
  float nlls = 0.f, cnts = 0.f;
#pragma unroll
  for (int j = 0; j < 4; j++) {
    int gr = rowbase + lq * 4 + j;
    int tt = gr >> 8, b = gr & 255;
    float m = -1e30f;
#pragma unroll
    for (int nt = 0; nt < 32; ++nt) m = fmaxf(m, acc[nt][j]);
    m = fmaxf(m, __shfl_xor(m, 1)); m = fmaxf(m, __shfl_xor(m, 2));
    m = fmaxf(m, __shfl_xor(m, 4)); m = fmaxf(m, __shfl_xor(m, 8));
    float s = 0.f;
#pragma unroll
    for (int nt = 0; nt < 32; ++nt) s += __expf(acc[nt][j] - m);
    s += __shfl_xor(s, 1); s += __shfl_xor(s, 2);
    s += __shfl_xor(s, 4); s += __shfl_xor(s, 8);
    float lse = m + __logf(s);
    int tg = atruth[b * TT + tt];
    int mk = bytemode ? (int)mb[b * TT + tt] : mi[b * TT + tt];
    if (((tg & 15) == lc) && mk) {
      float tl = 0.f;
#pragma unroll
      for (int nt = 0; nt < 32; ++nt) if (nt == (tg >> 4)) tl = acc[nt][j];  // static idx selects
      nlls += (lse - tl);
    }
    if (lc == 0 && mk) cnts += 1.f;
  }
#pragma unroll
  for (int off = 1; off < 64; off <<= 1) {
    nlls += __shfl_xor(nlls, off);
    cnts += __shfl_xor(cnts, off);
  }
  if (l == 0) {
    float* accf = (float*)(ws + WS_ACC);
    atomicAdd(&accf[0], nlls);
    atomicAdd(&accf[1], cnts);
  }
}

__global__ void k_final(const char* __restrict__ ws, float* __restrict__ out) {
  const float* accf = (const float*)(ws + WS_ACC);
  out[0] = accf[0] / accf[1];
}

extern "C" void kernel_launch(void* const* d_in, const int* in_sizes, int n_in,
                              void* d_out, int out_size, void* d_ws, size_t ws_size,
                              hipStream_t stream) {
  const float* x      = (const float*)d_in[0];
  const int*   atruth = (const int*)d_in[1];
  const void*  amask  = d_in[2];
  const float* emb    = (const float*)d_in[3];
  const float* W_ih   = (const float*)d_in[4];
  const float* W_hh   = (const float*)d_in[5];
  const float* b_ih   = (const float*)d_in[6];
  const float* b_hh   = (const float*)d_in[7];
  const float* W_out  = (const float*)d_in[8];
  const float* b_out  = (const float*)d_in[9];
  const float* h0     = (const float*)d_in[10];
  const float* c0     = (const float*)d_in[11];
  char* ws = (char*)d_ws;
  float* out = (float*)d_out;

  hipFuncSetAttribute((const void*)k_lstm, hipFuncAttributeMaxDynamicSharedMemorySize, 131072);
  hipFuncSetAttribute((const void*)k_logits, hipFuncAttributeMaxDynamicSharedMemorySize, 65536);

  // fp32 -> bf16 conversions
  k_f2bf8<<<dim3((G4 * DINk / 8 + 255) / 256), 256, 0, stream>>>(W_ih, (short*)(ws + WS_WIH), G4 * DINk / 8);
  k_f2bf8<<<dim3((NTAG * HH / 8 + 255) / 256), 256, 0, stream>>>(W_out, (short*)(ws + WS_WOUT), NTAG * HH / 8);
  k_f2bf8<<<dim3((BB * XD / 8 + 255) / 256), 256, 0, stream>>>(x, (short*)(ws + WS_XBF), BB * XD / 8);
  k_f2bf8<<<dim3((NTAG * CCG / 8 + 255) / 256), 256, 0, stream>>>(emb, (short*)(ws + WS_EMBBF), NTAG * CCG / 8);

  k_init<<<64, 256, 0, stream>>>(h0, (const int*)amask, ws);

  // xbase = x @ W_ih[:, :512]^T + b_ih + b_hh    [256, 4096]
  k_gemm<<<dim3(4, 64), 256, 0, stream>>>((short*)(ws + WS_XBF), XD, (short*)(ws + WS_WIH), DINk, 0,
                                          (float*)(ws + WS_XBASE), G4, XD / 32, b_ih, b_hh);
  // embproj = emb @ W_ih[:, 512:]^T              [512, 4096]
  k_gemm<<<dim3(8, 64), 256, 0, stream>>>((short*)(ws + WS_EMBBF), CCG, (short*)(ws + WS_WIH), DINk, XD,
                                          (float*)(ws + WS_EPROJ), G4, CCG / 32, nullptr, nullptr);

  k_lstm<<<256, 256, 131072, stream>>>(W_hh, atruth, c0, ws);

  k_logits<<<256, 256, 65536, stream>>>((short*)(ws + WS_HS), (short*)(ws + WS_WOUT), b_out,
                                        atruth, amask, ws);
  k_final<<<1, 1, 0, stream>>>(ws, out);
}

// Round 2
// 1044.214 us; speedup vs baseline: 1.1770x; 1.1770x over previous
//
#include <hip/hip_runtime.h>
#include <hip/hip_bf16.h>

#define BB 256
#define TT 64
#define XD 512
#define CCG 256
#define DINk 768
#define HH 1024
#define G4 4096
#define NTAG 512

typedef float f32x4 __attribute__((ext_vector_type(4)));
typedef short s16x8 __attribute__((ext_vector_type(8)));

// ---- workspace layout (bytes) ----
// hs: [TT+1][B][H] bf16 — slot 0 = h0, slot t+1 = h after step t. Doubles as the
// cross-WG exchange buffer (fresh addresses every step -> no stale-cache hazard).
#define WS_HS    0ull
#define WS_XBASE (WS_HS + (size_t)(TT+1)*BB*HH*2)    // 34 MiB
#define WS_EPROJ (WS_XBASE + (size_t)BB*G4*4)        // +4 MiB
#define WS_WIH   (WS_EPROJ + (size_t)NTAG*G4*4)      // +8 MiB
#define WS_WOUT  (WS_WIH + (size_t)G4*DINk*2)        // +6 MiB
#define WS_XBF   (WS_WOUT + (size_t)NTAG*HH*2)       // +1 MiB
#define WS_EMBBF (WS_XBF + (size_t)BB*XD*2)
#define WS_CNT   (WS_EMBBF + (size_t)NTAG*CCG*2)     // 256 ints barrier counters
#define WS_ACC   (WS_CNT + 1024)                     // nll_sum, mask_sum
#define WS_FLAG  (WS_ACC + 64)                       // mask-dtype flag

static __device__ __forceinline__ short f2bf(float f) {
  __hip_bfloat16 h = __float2bfloat16(f);
  return __builtin_bit_cast(short, h);
}

// device-coherent store: write-through to IF$ (visible agent-wide after vmcnt drain)
static __device__ __forceinline__ void store_dword_cc(void* p, unsigned v) {
  asm volatile("global_store_dword %0, %1, off sc0 sc1" :: "v"(p), "v"(v) : "memory");
}
// device-coherent load (bypasses L1+L2), serialized — used only for barrier polling
static __device__ __forceinline__ int load_int_cc(const void* p) {
  int r;
  asm volatile("global_load_dword %0, %1, off sc0 sc1\n\ts_waitcnt vmcnt(0)"
               : "=v"(r) : "v"(p) : "memory");
  return r;
}

// ---- generic fp32 -> bf16 convert, 8 elems/thread ----
__global__ void k_f2bf8(const float* __restrict__ in, short* __restrict__ out, int n8) {
  int i = blockIdx.x * blockDim.x + threadIdx.x;
  if (i >= n8) return;
  size_t idx = (size_t)i * 8;
  float4 a = *(const float4*)(in + idx);
  float4 b = *(const float4*)(in + idx + 4);
  s16x8 o;
  o[0]=f2bf(a.x); o[1]=f2bf(a.y); o[2]=f2bf(a.z); o[3]=f2bf(a.w);
  o[4]=f2bf(b.x); o[5]=f2bf(b.y); o[6]=f2bf(b.z); o[7]=f2bf(b.w);
  *(s16x8*)(out + idx) = o;
}

// ---- init: h0->bf16 hs slot0, zero counters/accumulators, detect mask dtype ----
__global__ void k_init(const float* __restrict__ h0, const int* __restrict__ mask_as_int,
                       char* __restrict__ ws) {
  int tid = blockIdx.x * blockDim.x + threadIdx.x;
  short* hb0 = (short*)(ws + WS_HS);
  for (int i = tid; i < BB * HH; i += gridDim.x * blockDim.x) hb0[i] = f2bf(h0[i]);
  if (blockIdx.x == 0) {
    int* cnt = (int*)(ws + WS_CNT);
    for (int i = threadIdx.x; i < 256; i += blockDim.x) cnt[i] = 0;
    int v = 0;
    for (int i = threadIdx.x; i < 4096; i += blockDim.x) v |= (mask_as_int[i] & ~1);
    __shared__ int red[256];
    red[threadIdx.x] = v;
    __syncthreads();
    if (threadIdx.x == 0) {
      int a = 0;
      for (int j = 0; j < 256; j++) a |= red[j];
      ((int*)(ws + WS_FLAG))[0] = (a != 0) ? 1 : 0;
      float* acc = (float*)(ws + WS_ACC);
      acc[0] = 0.f; acc[1] = 0.f;
    }
  }
}

// ---- simple bf16 MFMA GEMM: C[M][N] = A[M][K] * Bm[N][K]^T (+bias1+bias2) ----
__global__ __launch_bounds__(256) void k_gemm(const short* __restrict__ A, int lda,
    const short* __restrict__ Bm, int ldb, int bcol0,
    float* __restrict__ C, int ldc, int ksteps,
    const float* __restrict__ bias1, const float* __restrict__ bias2) {
  int w = threadIdx.x >> 6, l = threadIdx.x & 63;
  int lc = l & 15, lq = l >> 4;
  int arow = blockIdx.x * 64 + w * 16 + lc;
  f32x4 acc[4];
  const f32x4 z = {0.f, 0.f, 0.f, 0.f};
#pragma unroll
  for (int i = 0; i < 4; i++) acc[i] = z;
  const short* ap = A + (size_t)arow * lda + lq * 8;
  for (int kk = 0; kk < ksteps; ++kk) {
    s16x8 a = *(const s16x8*)(ap + kk * 32);
#pragma unroll
    for (int nt = 0; nt < 4; ++nt) {
      int brow = blockIdx.y * 64 + nt * 16 + lc;
      s16x8 b = *(const s16x8*)(Bm + (size_t)brow * ldb + bcol0 + kk * 32 + lq * 8);
      acc[nt] = __builtin_amdgcn_mfma_f32_16x16x32_bf16(a, b, acc[nt], 0, 0, 0);
    }
  }
#pragma unroll
  for (int nt = 0; nt < 4; ++nt) {
    int col = blockIdx.y * 64 + nt * 16 + lc;
    float badd = (bias1 ? bias1[col] : 0.f) + (bias2 ? bias2[col] : 0.f);
#pragma unroll
    for (int j = 0; j < 4; j++) {
      int r = blockIdx.x * 64 + w * 16 + lq * 4 + j;
      C[(size_t)r * ldc + col] = acc[nt][j] + badd;
    }
  }
}

// ---- persistent LSTM recurrence ----
// 256 WGs (1/CU). Group = 64 WGs over 64 batch rows; each WG owns 16 hidden cols.
// Waves: 2 row-halves x 2 gate-pairs. W_hh slice bf16 in 128 KiB LDS (swizzled);
// gate preacts exchanged via 17 KiB LDS (stride-68 padding). h exchange fence-free
// via sc0/sc1 write-through + relaxed agent atomics.
__global__ __launch_bounds__(256, 1) void k_lstm(const float* __restrict__ Whh,
    const int* __restrict__ atruth, const float* __restrict__ c0, char* __restrict__ ws) {
  extern __shared__ char sm[];
  float* pre = (float*)(sm + 131072);     // [64 rows][stride 68] : [g*16+col] within row
  const int bid = blockIdx.x;
  const int xcd = bid & 7, slot = bid >> 3;
  const int mg = xcd >> 1;               // batch group 0..3 (2 XCDs per group)
  const int hb = slot * 2 + (xcd & 1);   // hidden block 0..63
  const int tid = threadIdx.x;
  const int w = tid >> 6, l = tid & 63;
  const int lc = l & 15, lq = l >> 4;
  const int wy = w >> 1, wx = w & 1;     // row-half / gate-pair

  // stage W_hh slice -> LDS (bf16, swizzled): row r=g*16+rl at r*2048, byte k ^ ((rl&7)<<4)
  {
    const int r = tid >> 2, q = tid & 3;
    const int g = r >> 4, rl = r & 15;
    const float* src = Whh + (size_t)(g * HH + hb * 16 + rl) * HH + q * 256;
    const int swz = (rl & 7) << 4;
    char* dst = sm + r * 2048;
    for (int i = 0; i < 256; i += 8) {
      float4 f0 = *(const float4*)(src + i);
      float4 f1 = *(const float4*)(src + i + 4);
      s16x8 o;
      o[0]=f2bf(f0.x); o[1]=f2bf(f0.y); o[2]=f2bf(f0.z); o[3]=f2bf(f0.w);
      o[4]=f2bf(f1.x); o[5]=f2bf(f1.y); o[6]=f2bf(f1.z); o[7]=f2bf(f1.w);
      int koff = (q * 256 + i) * 2;
      *(s16x8*)(dst + (koff ^ swz)) = o;
    }
  }

  const int colbase = hb * 16;
  const float* xb = (const float*)(ws + WS_XBASE);
  const float* ep = (const float*)(ws + WS_EPROJ);
  short* hs = (short*)(ws + WS_HS);
  int* cnt = (int*)(ws + WS_CNT);

  // activation-thread mapping: 2 cols x 2 rows per thread
  const int acol = (tid & 7) * 2;        // 0..14
  const int ar0 = (tid >> 3) * 2;        // 0..62
  float cst[2][2];
  float xinv[2][4][2];
#pragma unroll
  for (int jr = 0; jr < 2; ++jr) {
    int br = mg * 64 + ar0 + jr;
#pragma unroll
    for (int jc = 0; jc < 2; ++jc) cst[jr][jc] = c0[(size_t)br * HH + colbase + acol + jc];
#pragma unroll
    for (int g = 0; g < 4; ++g)
#pragma unroll
      for (int jc = 0; jc < 2; ++jc)
        xinv[jr][g][jc] = xb[(size_t)br * G4 + g * HH + colbase + acol + jc];
  }

  const int swzl = (lc & 7) << 4;
  const char* bbase = sm + (size_t)(wx * 32 + lc) * 2048;  // gate rows {2wx,2wx+1}*16+lc
  __syncthreads();

  for (int t = 0; t < TT; ++t) {
    // ---- MFMA phase: gates(pair wx) for rows wy*32..+31 ----
    const f32x4 z = {0.f, 0.f, 0.f, 0.f};
    f32x4 acc00 = z, acc01 = z, acc10 = z, acc11 = z;
    const short* arowp = hs + (size_t)t * (BB * HH) + (size_t)(mg * 64 + wy * 32 + lc) * HH + lq * 8;
#pragma unroll 4
    for (int kk = 0; kk < 32; ++kk) {
      s16x8 a0 = *(const s16x8*)(arowp + kk * 32);
      s16x8 a1 = *(const s16x8*)(arowp + 16 * HH + kk * 32);
      const int kx = (kk * 64 + lq * 16) ^ swzl;
      s16x8 b0 = *(const s16x8*)(bbase + kx);
      s16x8 b1 = *(const s16x8*)(bbase + 16 * 2048 + kx);
      acc00 = __builtin_amdgcn_mfma_f32_16x16x32_bf16(a0, b0, acc00, 0, 0, 0);
      acc01 = __builtin_amdgcn_mfma_f32_16x16x32_bf16(a0, b1, acc01, 0, 0, 0);
      acc10 = __builtin_amdgcn_mfma_f32_16x16x32_bf16(a1, b0, acc10, 0, 0, 0);
      acc11 = __builtin_amdgcn_mfma_f32_16x16x32_bf16(a1, b1, acc11, 0, 0, 0);
    }
#pragma unroll
    for (int j = 0; j < 4; j++) {
      int r0 = wy * 32 + lq * 4 + j;
      pre[r0 * 68 + (wx * 2) * 16 + lc] = acc00[j];
      pre[r0 * 68 + (wx * 2 + 1) * 16 + lc] = acc01[j];
      pre[(r0 + 16) * 68 + (wx * 2) * 16 + lc] = acc10[j];
      pre[(r0 + 16) * 68 + (wx * 2 + 1) * 16 + lc] = acc11[j];
    }
    __syncthreads();  // pre ready

    // ---- activation phase ----
#pragma unroll
    for (int jr = 0; jr < 2; ++jr) {
      int r = ar0 + jr;
      int br = mg * 64 + r;
      int tok = (t == 0) ? 0 : atruth[br * TT + t - 1];
      const float* prow = pre + r * 68 + acol;
      const float* eprow = ep + (size_t)tok * G4 + colbase + acol;
      float2 p0 = *(const float2*)(prow);
      float2 p1 = *(const float2*)(prow + 16);
      float2 p2 = *(const float2*)(prow + 32);
      float2 p3 = *(const float2*)(prow + 48);
      float2 e0 = *(const float2*)(eprow);
      float2 e1 = *(const float2*)(eprow + HH);
      float2 e2 = *(const float2*)(eprow + 2 * HH);
      float2 e3 = *(const float2*)(eprow + 3 * HH);
      float pi[2] = {p0.x + e0.x + xinv[jr][0][0], p0.y + e0.y + xinv[jr][0][1]};
      float pf[2] = {p1.x + e1.x + xinv[jr][1][0], p1.y + e1.y + xinv[jr][1][1]};
      float pg[2] = {p2.x + e2.x + xinv[jr][2][0], p2.y + e2.y + xinv[jr][2][1]};
      float po[2] = {p3.x + e3.x + xinv[jr][3][0], p3.y + e3.y + xinv[jr][3][1]};
      unsigned short hb16[2];
#pragma unroll
      for (int jc = 0; jc < 2; ++jc) {
        float iv = 1.f / (1.f + __expf(-pi[jc]));
        float fv = 1.f / (1.f + __expf(-pf[jc]));
        float gv = tanhf(pg[jc]);
        float ov = 1.f / (1.f + __expf(-po[jc]));
        float cv = fv * cst[jr][jc] + iv * gv;
        cst[jr][jc] = cv;
        hb16[jc] = (unsigned short)f2bf(ov * tanhf(cv));
      }
      unsigned hpack = (unsigned)hb16[0] | ((unsigned)hb16[1] << 16);
      store_dword_cc(hs + ((size_t)(t + 1) * BB + br) * HH + colbase + acol, hpack);
    }

    asm volatile("s_waitcnt vmcnt(0)" ::: "memory");
    __syncthreads();  // stores drained; pre reads done
    if (t < TT - 1) {
      if (tid == 0) {
        int* c = &cnt[mg * 64 + t];
        __hip_atomic_fetch_add(c, 1, __ATOMIC_RELAXED, __HIP_MEMORY_SCOPE_AGENT);
        while (load_int_cc(c) < 64) __builtin_amdgcn_s_sleep(2);
      }
      __syncthreads();
    }
  }
}

// ---- logits + fused log-softmax + masked NLL partial sums ----
__global__ __launch_bounds__(256, 1) void k_logits(const short* __restrict__ hsb,
    const short* __restrict__ Wo, const float* __restrict__ bout,
    const int* __restrict__ atruth, const void* __restrict__ maskp,
    char* __restrict__ ws) {
  extern __shared__ char sm[];
  const int tid = threadIdx.x;
  const int w = tid >> 6, l = tid & 63;
  const int lc = l & 15, lq = l >> 4;
  const int rowbase = blockIdx.x * 64 + w * 16;
  f32x4 acc[32];
#pragma unroll
  for (int nt = 0; nt < 32; ++nt) {
    float bv = bout[nt * 16 + lc];
    f32x4 tmp = {bv, bv, bv, bv};
    acc[nt] = tmp;
  }
  const int swzl = (lc & 7) << 4;
  for (int kb = 0; kb < 16; ++kb) {
    __syncthreads();
    {
      const int r0 = tid >> 3, q = tid & 7;
#pragma unroll
      for (int i = 0; i < 16; i++) {
        int r = r0 + 32 * i;
        s16x8 v = *(const s16x8*)(Wo + (size_t)r * HH + kb * 64 + q * 8);
        *(s16x8*)(sm + r * 128 + ((q * 16) ^ ((r & 7) << 4))) = v;
      }
    }
    __syncthreads();
#pragma unroll
    for (int ks = 0; ks < 2; ++ks) {
      s16x8 a = *(const s16x8*)(hsb + (size_t)(rowbase + lc) * HH + kb * 64 + ks * 32 + lq * 8);
      const int kx = (ks * 64 + lq * 16) ^ swzl;
#pragma unroll
      for (int nt = 0; nt < 32; ++nt) {
        s16x8 b = *(const s16x8*)(sm + (nt * 16 + lc) * 128 + kx);
        acc[nt] = __builtin_amdgcn_mfma_f32_16x16x32_bf16(a, b, acc[nt], 0, 0, 0);
      }
    }
  }
  const int bytemode = ((const int*)(ws + WS_FLAG))[0];
  const unsigned char* mb = (const unsigned char*)maskp;
  const int* mi = (const int*)maskp;
  float nlls = 0.f, cnts = 0.f;
#pragma unroll
  for (int j = 0; j < 4; j++) {
    int gr = rowbase + lq * 4 + j;
    int tt = gr >> 8, b = gr & 255;
    float m = -1e30f;
#pragma unroll
    for (int nt = 0; nt < 32; ++nt) m = fmaxf(m, acc[nt][j]);
    m = fmaxf(m, __shfl_xor(m, 1)); m = fmaxf(m, __shfl_xor(m, 2));
    m = fmaxf(m, __shfl_xor(m, 4)); m = fmaxf(m, __shfl_xor(m, 8));
    float s = 0.f;
#pragma unroll
    for (int nt = 0; nt < 32; ++nt) s += __expf(acc[nt][j] - m);
    s += __shfl_xor(s, 1); s += __shfl_xor(s, 2);
    s += __shfl_xor(s, 4); s += __shfl_xor(s, 8);
    float lse = m + __logf(s);
    int tg = atruth[b * TT + tt];
    int mk = bytemode ? (int)mb[b * TT + tt] : mi[b * TT + tt];
    if (((tg & 15) == lc) && mk) {
      float tl = 0.f;
#pragma unroll
      for (int nt = 0; nt < 32; ++nt) if (nt == (tg >> 4)) tl = acc[nt][j];
      nlls += (lse - tl);
    }
    if (lc == 0 && mk) cnts += 1.f;
  }
#pragma unroll
  for (int off = 1; off < 64; off <<= 1) {
    nlls += __shfl_xor(nlls, off);
    cnts += __shfl_xor(cnts, off);
  }
  if (l == 0) {
    float* accf = (float*)(ws + WS_ACC);
    atomicAdd(&accf[0], nlls);
    atomicAdd(&accf[1], cnts);
  }
}

__global__ void k_final(const char* __restrict__ ws, float* __restrict__ out) {
  const float* accf = (const float*)(ws + WS_ACC);
  out[0] = accf[0] / accf[1];
}

extern "C" void kernel_launch(void* const* d_in, const int* in_sizes, int n_in,
                              void* d_out, int out_size, void* d_ws, size_t ws_size,
                              hipStream_t stream) {
  const float* x      = (const float*)d_in[0];
  const int*   atruth = (const int*)d_in[1];
  const void*  amask  = d_in[2];
  const float* emb    = (const float*)d_in[3];
  const float* W_ih   = (const float*)d_in[4];
  const float* W_hh   = (const float*)d_in[5];
  const float* b_ih   = (const float*)d_in[6];
  const float* b_hh   = (const float*)d_in[7];
  const float* W_out  = (const float*)d_in[8];
  const float* b_out  = (const float*)d_in[9];
  const float* h0     = (const float*)d_in[10];
  const float* c0     = (const float*)d_in[11];
  char* ws = (char*)d_ws;
  float* out = (float*)d_out;

  hipFuncSetAttribute((const void*)k_lstm, hipFuncAttributeMaxDynamicSharedMemorySize, 149504);
  hipFuncSetAttribute((const void*)k_logits, hipFuncAttributeMaxDynamicSharedMemorySize, 65536);

  k_f2bf8<<<dim3((G4 * DINk / 8 + 255) / 256), 256, 0, stream>>>(W_ih, (short*)(ws + WS_WIH), G4 * DINk / 8);
  k_f2bf8<<<dim3((NTAG * HH / 8 + 255) / 256), 256, 0, stream>>>(W_out, (short*)(ws + WS_WOUT), NTAG * HH / 8);
  k_f2bf8<<<dim3((BB * XD / 8 + 255) / 256), 256, 0, stream>>>(x, (short*)(ws + WS_XBF), BB * XD / 8);
  k_f2bf8<<<dim3((NTAG * CCG / 8 + 255) / 256), 256, 0, stream>>>(emb, (short*)(ws + WS_EMBBF), NTAG * CCG / 8);

  k_init<<<64, 256, 0, stream>>>(h0, (const int*)amask, ws);

  // xbase = x @ W_ih[:, :512]^T + b_ih + b_hh    [256, 4096]
  k_gemm<<<dim3(4, 64), 256, 0, stream>>>((short*)(ws + WS_XBF), XD, (short*)(ws + WS_WIH), DINk, 0,
                                          (float*)(ws + WS_XBASE), G4, XD / 32, b_ih, b_hh);
  // embproj = emb @ W_ih[:, 512:]^T              [512, 4096]
  k_gemm<<<dim3(8, 64), 256, 0, stream>>>((short*)(ws + WS_EMBBF), CCG, (short*)(ws + WS_WIH), DINk, XD,
                                          (float*)(ws + WS_EPROJ), G4, CCG / 32, nullptr, nullptr);

  k_lstm<<<256, 256, 148480, stream>>>(W_hh, atruth, c0, ws);

  k_logits<<<256, 256, 65536, stream>>>((short*)(ws + WS_HS) + BB * HH, (short*)(ws + WS_WOUT), b_out,
                                        atruth, amask, ws);
  k_final<<<1, 1, 0, stream>>>(ws, out);
}

// Round 3
// 802.821 us; speedup vs baseline: 1.5309x; 1.3007x over previous
//
#include <hip/hip_runtime.h>
#include <hip/hip_bf16.h>

#define BB 256
#define TT 64
#define XD 512
#define CCG 256
#define DINk 768
#define HH 1024
#define G4 4096
#define NTAG 512

typedef float f32x4 __attribute__((ext_vector_type(4)));
typedef short s16x8 __attribute__((ext_vector_type(8)));

// ---- workspace layout (bytes) ----
#define WS_HS    0ull                                 // [TT+1][B][H] bf16 (slot0=h0)
#define WS_XBASE (WS_HS + (size_t)(TT+1)*BB*HH*2)
#define WS_EPROJ (WS_XBASE + (size_t)BB*G4*4)
#define WS_WIH   (WS_EPROJ + (size_t)NTAG*G4*4)
#define WS_WOUT  (WS_WIH + (size_t)G4*DINk*2)
#define WS_XBF   (WS_WOUT + (size_t)NTAG*HH*2)
#define WS_EMBBF (WS_XBF + (size_t)BB*XD*2)
#define WS_CNT   (WS_EMBBF + (size_t)NTAG*CCG*2)      // 256 flag ints
#define WS_ACC   (WS_CNT + 1024)
#define WS_FLAG  (WS_ACC + 64)
#define WS_XPROJ (WS_FLAG + 64)                       // [T][B][4H] bf16 = 128 MiB

static __device__ __forceinline__ short f2bf(float f) {
  __hip_bfloat16 h = __float2bfloat16(f);
  return __builtin_bit_cast(short, h);
}
static __device__ __forceinline__ float bf2f(unsigned short u) {
  unsigned x = ((unsigned)u) << 16;
  return __builtin_bit_cast(float, x);
}
// device-coherent store (write-through to coherence point)
static __device__ __forceinline__ void store_dword_cc(void* p, unsigned v) {
  asm volatile("global_store_dword %0, %1, off sc0 sc1" :: "v"(p), "v"(v) : "memory");
}
// device-coherent load (bypasses L1/L2)
static __device__ __forceinline__ int load_int_cc(const void* p) {
  int r;
  asm volatile("global_load_dword %0, %1, off sc0 sc1\n\ts_waitcnt vmcnt(0)"
               : "=v"(r) : "v"(p) : "memory");
  return r;
}

__global__ void k_f2bf8(const float* __restrict__ in, short* __restrict__ out, int n8) {
  int i = blockIdx.x * blockDim.x + threadIdx.x;
  if (i >= n8) return;
  size_t idx = (size_t)i * 8;
  float4 a = *(const float4*)(in + idx);
  float4 b = *(const float4*)(in + idx + 4);
  s16x8 o;
  o[0]=f2bf(a.x); o[1]=f2bf(a.y); o[2]=f2bf(a.z); o[3]=f2bf(a.w);
  o[4]=f2bf(b.x); o[5]=f2bf(b.y); o[6]=f2bf(b.z); o[7]=f2bf(b.w);
  *(s16x8*)(out + idx) = o;
}

__global__ void k_init(const float* __restrict__ h0, const int* __restrict__ mask_as_int,
                       char* __restrict__ ws) {
  int tid = blockIdx.x * blockDim.x + threadIdx.x;
  short* hb0 = (short*)(ws + WS_HS);
  for (int i = tid; i < BB * HH; i += gridDim.x * blockDim.x) hb0[i] = f2bf(h0[i]);
  if (blockIdx.x == 0) {
    int* cnt = (int*)(ws + WS_CNT);
    for (int i = threadIdx.x; i < 256; i += blockDim.x) cnt[i] = 0;
    int v = 0;
    for (int i = threadIdx.x; i < 4096; i += blockDim.x) v |= (mask_as_int[i] & ~1);
    __shared__ int red[256];
    red[threadIdx.x] = v;
    __syncthreads();
    if (threadIdx.x == 0) {
      int a = 0;
      for (int j = 0; j < 256; j++) a |= red[j];
      ((int*)(ws + WS_FLAG))[0] = (a != 0) ? 1 : 0;
      float* acc = (float*)(ws + WS_ACC);
      acc[0] = 0.f; acc[1] = 0.f;
    }
  }
}

// xproj[t][b][:] = xbase[b][:] + eproj[prev_tok(b,t)][:]  (bf16 out)
__global__ __launch_bounds__(256) void k_xproj(const float* __restrict__ xbase,
    const float* __restrict__ eproj, const int* __restrict__ atruth,
    short* __restrict__ xproj) {
  int bid = blockIdx.x;
  int t = bid & 63, b = bid >> 6;
  int tok = (t == 0) ? 0 : atruth[b * TT + t - 1];
  const float* xs = xbase + (size_t)b * G4 + threadIdx.x * 16;
  const float* es = eproj + (size_t)tok * G4 + threadIdx.x * 16;
  short* dst = xproj + ((size_t)t * BB + b) * G4 + threadIdx.x * 16;
#pragma unroll
  for (int i = 0; i < 16; i += 8) {
    float4 x0 = *(const float4*)(xs + i);
    float4 x1 = *(const float4*)(xs + i + 4);
    float4 e0 = *(const float4*)(es + i);
    float4 e1 = *(const float4*)(es + i + 4);
    s16x8 o;
    o[0]=f2bf(x0.x+e0.x); o[1]=f2bf(x0.y+e0.y); o[2]=f2bf(x0.z+e0.z); o[3]=f2bf(x0.w+e0.w);
    o[4]=f2bf(x1.x+e1.x); o[5]=f2bf(x1.y+e1.y); o[6]=f2bf(x1.z+e1.z); o[7]=f2bf(x1.w+e1.w);
    *(s16x8*)(dst + i) = o;
  }
}

// ---- simple bf16 MFMA GEMM: C[M][N] = A[M][K] * Bm[N][K]^T (+bias1+bias2) ----
__global__ __launch_bounds__(256) void k_gemm(const short* __restrict__ A, int lda,
    const short* __restrict__ Bm, int ldb, int bcol0,
    float* __restrict__ C, int ldc, int ksteps,
    const float* __restrict__ bias1, const float* __restrict__ bias2) {
  int w = threadIdx.x >> 6, l = threadIdx.x & 63;
  int lc = l & 15, lq = l >> 4;
  int arow = blockIdx.x * 64 + w * 16 + lc;
  f32x4 acc[4];
  const f32x4 z = {0.f, 0.f, 0.f, 0.f};
#pragma unroll
  for (int i = 0; i < 4; i++) acc[i] = z;
  const short* ap = A + (size_t)arow * lda + lq * 8;
  for (int kk = 0; kk < ksteps; ++kk) {
    s16x8 a = *(const s16x8*)(ap + kk * 32);
#pragma unroll
    for (int nt = 0; nt < 4; ++nt) {
      int brow = blockIdx.y * 64 + nt * 16 + lc;
      s16x8 b = *(const s16x8*)(Bm + (size_t)brow * ldb + bcol0 + kk * 32 + lq * 8);
      acc[nt] = __builtin_amdgcn_mfma_f32_16x16x32_bf16(a, b, acc[nt], 0, 0, 0);
    }
  }
#pragma unroll
  for (int nt = 0; nt < 4; ++nt) {
    int col = blockIdx.y * 64 + nt * 16 + lc;
    float badd = (bias1 ? bias1[col] : 0.f) + (bias2 ? bias2[col] : 0.f);
#pragma unroll
    for (int j = 0; j < 4; j++) {
      int r = blockIdx.x * 64 + w * 16 + lq * 4 + j;
      C[(size_t)r * ldc + col] = acc[nt][j] + badd;
    }
  }
}

// ---- persistent LSTM recurrence ----
// 256 WGs (1/CU), 512 threads (8 waves = 2/SIMD). Group = 64 WGs over 64 batch
// rows (2 XCDs); each WG owns 16 hidden cols. Waves: 4 row-slabs x 2 gate-pairs.
// W_hh slice bf16 in 128 KiB LDS (swizzled). xproj prefetched into LDS during
// MFMA. Barrier: per-WG flags + lane-parallel poll (no atomic contention).
__global__ __launch_bounds__(512, 2) void k_lstm(const float* __restrict__ Whh,
    const short* __restrict__ xproj, const float* __restrict__ c0,
    char* __restrict__ ws) {
  extern __shared__ char sm[];
  float* pre = (float*)(sm + 131072);          // [64][stride 67] f32
  short* xbuf = (short*)(sm + 131072 + 17152); // [64][stride 72] bf16
  const int bid = blockIdx.x;
  const int xcd = bid & 7, slot = bid >> 3;
  const int mg = xcd >> 1;                     // batch group 0..3
  const int hb = slot * 2 + (xcd & 1);         // hidden block 0..63
  const int wgid = (xcd & 1) * 32 + slot;      // id within group 0..63
  const int tid = threadIdx.x;
  const int w = tid >> 6, l = tid & 63;
  const int lc = l & 15, lq = l >> 4;
  const int wy = w >> 1, wx = w & 1;           // row-slab(16) / gate-pair

  // stage W_hh slice -> LDS (bf16, swizzled): row r=g*16+rl at r*2048, byte k ^ ((rl&7)<<4)
  {
    const int r = tid >> 3, q = tid & 7;
    const int g = r >> 4, rl = r & 15;
    const float* src = Whh + (size_t)(g * HH + hb * 16 + rl) * HH + q * 128;
    const int swz = (rl & 7) << 4;
    char* dst = sm + r * 2048;
#pragma unroll
    for (int i = 0; i < 128; i += 8) {
      float4 f0 = *(const float4*)(src + i);
      float4 f1 = *(const float4*)(src + i + 4);
      s16x8 o;
      o[0]=f2bf(f0.x); o[1]=f2bf(f0.y); o[2]=f2bf(f0.z); o[3]=f2bf(f0.w);
      o[4]=f2bf(f1.x); o[5]=f2bf(f1.y); o[6]=f2bf(f1.z); o[7]=f2bf(f1.w);
      int koff = (q * 128 + i) * 2;
      *(s16x8*)(dst + (koff ^ swz)) = o;
    }
  }

  const int colbase = hb * 16;
  short* hs = (short*)(ws + WS_HS);
  int* flags = (int*)(ws + WS_CNT);

  // activation mapping: row = tid>>3 (0..63), col-pair = tid&7
  const int ar = tid >> 3, cp = tid & 7;
  const int abr = mg * 64 + ar;
  float cst[2];
  cst[0] = c0[(size_t)abr * HH + colbase + 2 * cp];
  cst[1] = c0[(size_t)abr * HH + colbase + 2 * cp + 1];

  const int swzl = (lc & 7) << 4;
  const char* bbase = sm + (size_t)(wx * 32 + lc) * 2048;
  const int piece = tid & 7;                  // prefetch: gate=piece>>1, half=piece&1
  const short* xsrc0 = xproj + (size_t)(mg * 64 + (tid >> 3)) * G4 +
                       (piece >> 1) * HH + colbase + (piece & 1) * 8;
  __syncthreads();

  for (int t = 0; t < TT; ++t) {
    // prefetch this step's xproj slice (independent of h) — issue before poll
    s16x8 xv = *(const s16x8*)(xsrc0 + (size_t)t * (BB * G4));

    if (t) {  // wait for hs[t] from all WGs in group (per-wave poll)
      const int* f = flags + mg * 64 + l;
      for (;;) {
        int v = load_int_cc(f);
        if (__all(v >= t)) break;
        __builtin_amdgcn_s_sleep(2);
      }
    }

    // ---- MFMA: rows wy*16..+15, gate-pair wx ----
    const f32x4 z = {0.f, 0.f, 0.f, 0.f};
    f32x4 acc0 = z, acc1 = z;
    const short* arowp = hs + (size_t)t * (BB * HH) + (size_t)(mg * 64 + wy * 16 + lc) * HH + lq * 8;
#pragma unroll 8
    for (int kk = 0; kk < 32; ++kk) {
      s16x8 a = *(const s16x8*)(arowp + kk * 32);
      const int kx = (kk * 64 + lq * 16) ^ swzl;
      acc0 = __builtin_amdgcn_mfma_f32_16x16x32_bf16(a, *(const s16x8*)(bbase + kx), acc0, 0, 0, 0);
      acc1 = __builtin_amdgcn_mfma_f32_16x16x32_bf16(a, *(const s16x8*)(bbase + 16 * 2048 + kx), acc1, 0, 0, 0);
    }
    asm volatile("s_waitcnt vmcnt(0)" ::: "memory");  // xv + a-loads complete
#pragma unroll
    for (int j = 0; j < 4; j++) {
      int r = wy * 16 + lq * 4 + j;
      pre[r * 67 + wx * 32 + lc] = acc0[j];
      pre[r * 67 + wx * 32 + 16 + lc] = acc1[j];
    }
    *(s16x8*)(xbuf + (tid >> 3) * 72 + (piece >> 1) * 16 + (piece & 1) * 8) = xv;
    __syncthreads();

    // ---- activation: 1 row x 2 cols ----
    {
      const float* prow = pre + ar * 67 + 2 * cp;
      const short* xrow = xbuf + ar * 72 + 2 * cp;
      unsigned short h16[2];
#pragma unroll
      for (int jc = 0; jc < 2; ++jc) {
        float pi = prow[jc]      + bf2f((unsigned short)xrow[jc]);
        float pf = prow[16 + jc] + bf2f((unsigned short)xrow[16 + jc]);
        float pg = prow[32 + jc] + bf2f((unsigned short)xrow[32 + jc]);
        float po = prow[48 + jc] + bf2f((unsigned short)xrow[48 + jc]);
        float iv = 1.f / (1.f + __expf(-pi));
        float fv = 1.f / (1.f + __expf(-pf));
        float gv = 1.f - 2.f / (1.f + __expf(2.f * pg));   // tanh
        float ov = 1.f / (1.f + __expf(-po));
        float cv = fv * cst[jc] + iv * gv;
        cst[jc] = cv;
        float th = 1.f - 2.f / (1.f + __expf(2.f * cv));   // tanh(c)
        h16[jc] = (unsigned short)f2bf(ov * th);
      }
      unsigned hpack = (unsigned)h16[0] | ((unsigned)h16[1] << 16);
      store_dword_cc(hs + ((size_t)(t + 1) * BB + abr) * HH + colbase + 2 * cp, hpack);
    }
    asm volatile("s_waitcnt vmcnt(0)" ::: "memory");  // h stores drained (per wave)
    __syncthreads();                                   // all waves drained
    if (tid == 0 && t < TT - 1) {
      store_dword_cc(flags + mg * 64 + wgid, t + 1);
    }
  }
}

// ---- logits + fused log-softmax + masked NLL partial sums ----
__global__ __launch_bounds__(256, 1) void k_logits(const short* __restrict__ hsb,
    const short* __restrict__ Wo, const float* __restrict__ bout,
    const int* __restrict__ atruth, const void* __restrict__ maskp,
    char* __restrict__ ws) {
  extern __shared__ char sm[];
  const int tid = threadIdx.x;
  const int w = tid >> 6, l = tid & 63;
  const int lc = l & 15, lq = l >> 4;
  const int rowbase = blockIdx.x * 64 + w * 16;
  f32x4 acc[32];
#pragma unroll
  for (int nt = 0; nt < 32; ++nt) {
    float bv = bout[nt * 16 + lc];
    f32x4 tmp = {bv, bv, bv, bv};
    acc[nt] = tmp;
  }
  const int swzl = (lc & 7) << 4;
  for (int kb = 0; kb < 16; ++kb) {
    __syncthreads();
    {
      const int r0 = tid >> 3, q = tid & 7;
#pragma unroll
      for (int i = 0; i < 16; i++) {
        int r = r0 + 32 * i;
        s16x8 v = *(const s16x8*)(Wo + (size_t)r * HH + kb * 64 + q * 8);
        *(s16x8*)(sm + r * 128 + ((q * 16) ^ ((r & 7) << 4))) = v;
      }
    }
    __syncthreads();
#pragma unroll
    for (int ks = 0; ks < 2; ++ks) {
      s16x8 a = *(const s16x8*)(hsb + (size_t)(rowbase + lc) * HH + kb * 64 + ks * 32 + lq * 8);
      const int kx = (ks * 64 + lq * 16) ^ swzl;
#pragma unroll
      for (int nt = 0; nt < 32; ++nt) {
        s16x8 b = *(const s16x8*)(sm + (nt * 16 + lc) * 128 + kx);
        acc[nt] = __builtin_amdgcn_mfma_f32_16x16x32_bf16(a, b, acc[nt], 0, 0, 0);
      }
    }
  }
  const int bytemode = ((const int*)(ws + WS_FLAG))[0];
  const unsigned char* mb = (const unsigned char*)maskp;
  const int* mi = (const int*)maskp;
  float nlls = 0.f, cnts = 0.f;
#pragma unroll
  for (int j = 0; j < 4; j++) {
    int gr = rowbase + lq * 4 + j;
    int tt = gr >> 8, b = gr & 255;
    float m = -1e30f;
#pragma unroll
    for (int nt = 0; nt < 32; ++nt) m = fmaxf(m, acc[nt][j]);
    m = fmaxf(m, __shfl_xor(m, 1)); m = fmaxf(m, __shfl_xor(m, 2));
    m = fmaxf(m, __shfl_xor(m, 4)); m = fmaxf(m, __shfl_xor(m, 8));
    float s = 0.f;
#pragma unroll
    for (int nt = 0; nt < 32; ++nt) s += __expf(acc[nt][j] - m);
    s += __shfl_xor(s, 1); s += __shfl_xor(s, 2);
    s += __shfl_xor(s, 4); s += __shfl_xor(s, 8);
    float lse = m + __logf(s);
    int tg = atruth[b * TT + tt];
    int mk = bytemode ? (int)mb[b * TT + tt] : mi[b * TT + tt];
    if (((tg & 15) == lc) && mk) {
      float tl = 0.f;
#pragma unroll
      for (int nt = 0; nt < 32; ++nt) if (nt == (tg >> 4)) tl = acc[nt][j];
      nlls += (lse - tl);
    }
    if (lc == 0 && mk) cnts += 1.f;
  }
#pragma unroll
  for (int off = 1; off < 64; off <<= 1) {
    nlls += __shfl_xor(nlls, off);
    cnts += __shfl_xor(cnts, off);
  }
  if (l == 0) {
    float* accf = (float*)(ws + WS_ACC);
    atomicAdd(&accf[0], nlls);
    atomicAdd(&accf[1], cnts);
  }
}

__global__ void k_final(const char* __restrict__ ws, float* __restrict__ out) {
  const float* accf = (const float*)(ws + WS_ACC);
  out[0] = accf[0] / accf[1];
}

extern "C" void kernel_launch(void* const* d_in, const int* in_sizes, int n_in,
                              void* d_out, int out_size, void* d_ws, size_t ws_size,
                              hipStream_t stream) {
  const float* x      = (const float*)d_in[0];
  const int*   atruth = (const int*)d_in[1];
  const void*  amask  = d_in[2];
  const float* emb    = (const float*)d_in[3];
  const float* W_ih   = (const float*)d_in[4];
  const float* W_hh   = (const float*)d_in[5];
  const float* b_ih   = (const float*)d_in[6];
  const float* b_hh   = (const float*)d_in[7];
  const float* W_out  = (const float*)d_in[8];
  const float* b_out  = (const float*)d_in[9];
  const float* h0     = (const float*)d_in[10];
  const float* c0     = (const float*)d_in[11];
  char* ws = (char*)d_ws;
  float* out = (float*)d_out;

  hipFuncSetAttribute((const void*)k_lstm, hipFuncAttributeMaxDynamicSharedMemorySize, 157440);
  hipFuncSetAttribute((const void*)k_logits, hipFuncAttributeMaxDynamicSharedMemorySize, 65536);

  k_f2bf8<<<dim3((G4 * DINk / 8 + 255) / 256), 256, 0, stream>>>(W_ih, (short*)(ws + WS_WIH), G4 * DINk / 8);
  k_f2bf8<<<dim3((NTAG * HH / 8 + 255) / 256), 256, 0, stream>>>(W_out, (short*)(ws + WS_WOUT), NTAG * HH / 8);
  k_f2bf8<<<dim3((BB * XD / 8 + 255) / 256), 256, 0, stream>>>(x, (short*)(ws + WS_XBF), BB * XD / 8);
  k_f2bf8<<<dim3((NTAG * CCG / 8 + 255) / 256), 256, 0, stream>>>(emb, (short*)(ws + WS_EMBBF), NTAG * CCG / 8);

  k_init<<<64, 256, 0, stream>>>(h0, (const int*)amask, ws);

  // xbase = x @ W_ih[:, :512]^T + b_ih + b_hh    [256, 4096] f32
  k_gemm<<<dim3(4, 64), 256, 0, stream>>>((short*)(ws + WS_XBF), XD, (short*)(ws + WS_WIH), DINk, 0,
                                          (float*)(ws + WS_XBASE), G4, XD / 32, b_ih, b_hh);
  // embproj = emb @ W_ih[:, 512:]^T              [512, 4096] f32
  k_gemm<<<dim3(8, 64), 256, 0, stream>>>((short*)(ws + WS_EMBBF), CCG, (short*)(ws + WS_WIH), DINk, XD,
                                          (float*)(ws + WS_EPROJ), G4, CCG / 32, nullptr, nullptr);

  // xproj[t][b] = xbase[b] + eproj[prev_tok]  (bf16)
  k_xproj<<<dim3(BB * TT), 256, 0, stream>>>((const float*)(ws + WS_XBASE),
                                             (const float*)(ws + WS_EPROJ), atruth,
                                             (short*)(ws + WS_XPROJ));

  k_lstm<<<256, 512, 157440, stream>>>(W_hh, (const short*)(ws + WS_XPROJ), c0, ws);

  k_logits<<<256, 256, 65536, stream>>>((short*)(ws + WS_HS) + BB * HH, (short*)(ws + WS_WOUT), b_out,
                                        atruth, amask, ws);
  k_final<<<1, 1, 0, stream>>>(ws, out);
}

// Round 4
// 589.756 us; speedup vs baseline: 2.0840x; 1.3613x over previous
//
#include <hip/hip_runtime.h>
#include <hip/hip_bf16.h>

#define BB 256
#define TT 64
#define XD 512
#define CCG 256
#define DINk 768
#define HH 1024
#define G4 4096
#define NTAG 512

typedef float f32x4 __attribute__((ext_vector_type(4)));
typedef short s16x8 __attribute__((ext_vector_type(8)));
typedef short s16x4 __attribute__((ext_vector_type(4)));

// ---- workspace layout (bytes) ----
#define WS_HS    0ull                                 // [TT+1][B][H] bf16 (slot0=h0)
#define WS_XBASE (WS_HS + (size_t)(TT+1)*BB*HH*2)     // xbase bf16 [256][4096]
#define WS_EPROJ (WS_XBASE + (size_t)BB*G4*4)         // eproj bf16 [512][4096]
#define WS_WIH   (WS_EPROJ + (size_t)NTAG*G4*4)
#define WS_WOUT  (WS_WIH + (size_t)G4*DINk*2)
#define WS_XBF   (WS_WOUT + (size_t)NTAG*HH*2)
#define WS_EMBBF (WS_XBF + (size_t)BB*XD*2)
#define WS_CNT   (WS_EMBBF + (size_t)NTAG*CCG*2)      // 256 flag ints
#define WS_ACC   (WS_CNT + 1024)
#define WS_FLAG  (WS_ACC + 64)
#define WS_XPROJ (WS_FLAG + 64)                       // [T][4096 gc][256 b] bf16 = 128 MiB

static __device__ __forceinline__ short f2bf(float f) {
  __hip_bfloat16 h = __float2bfloat16(f);
  return __builtin_bit_cast(short, h);
}
static __device__ __forceinline__ float bf2f(unsigned short u) {
  unsigned x = ((unsigned)u) << 16;
  return __builtin_bit_cast(float, x);
}
// device-coherent stores (write-through to coherence point / IF$)
static __device__ __forceinline__ void store_dword_cc(void* p, unsigned v) {
  asm volatile("global_store_dword %0, %1, off sc0 sc1" :: "v"(p), "v"(v) : "memory");
}
static __device__ __forceinline__ void store_short_cc(void* p, unsigned v) {
  asm volatile("global_store_short %0, %1, off sc0 sc1" :: "v"(p), "v"(v) : "memory");
}
// device-coherent load (bypasses L1/L2)
static __device__ __forceinline__ int load_int_cc(const void* p) {
  int r;
  asm volatile("global_load_dword %0, %1, off sc0 sc1\n\ts_waitcnt vmcnt(0)"
               : "=v"(r) : "v"(p) : "memory");
  return r;
}
static __device__ __forceinline__ float fsig(float x) {  // sigmoid
  return __builtin_amdgcn_rcpf(1.f + __expf(-x));
}
static __device__ __forceinline__ float ftanh(float x) {
  return 1.f - 2.f * __builtin_amdgcn_rcpf(1.f + __expf(2.f * x));
}

__global__ void k_f2bf8(const float* __restrict__ in, short* __restrict__ out, int n8) {
  int i = blockIdx.x * blockDim.x + threadIdx.x;
  if (i >= n8) return;
  size_t idx = (size_t)i * 8;
  float4 a = *(const float4*)(in + idx);
  float4 b = *(const float4*)(in + idx + 4);
  s16x8 o;
  o[0]=f2bf(a.x); o[1]=f2bf(a.y); o[2]=f2bf(a.z); o[3]=f2bf(a.w);
  o[4]=f2bf(b.x); o[5]=f2bf(b.y); o[6]=f2bf(b.z); o[7]=f2bf(b.w);
  *(s16x8*)(out + idx) = o;
}

__global__ void k_init(const float* __restrict__ h0, const int* __restrict__ mask_as_int,
                       char* __restrict__ ws) {
  int tid = blockIdx.x * blockDim.x + threadIdx.x;
  short* hb0 = (short*)(ws + WS_HS);
  for (int i = tid; i < BB * HH; i += gridDim.x * blockDim.x) hb0[i] = f2bf(h0[i]);
  if (blockIdx.x == 0) {
    int* cnt = (int*)(ws + WS_CNT);
    for (int i = threadIdx.x; i < 256; i += blockDim.x) cnt[i] = 0;
    int v = 0;
    for (int i = threadIdx.x; i < 4096; i += blockDim.x) v |= (mask_as_int[i] & ~1);
    __shared__ int red[256];
    red[threadIdx.x] = v;
    __syncthreads();
    if (threadIdx.x == 0) {
      int a = 0;
      for (int j = 0; j < 256; j++) a |= red[j];
      ((int*)(ws + WS_FLAG))[0] = (a != 0) ? 1 : 0;
      float* acc = (float*)(ws + WS_ACC);
      acc[0] = 0.f; acc[1] = 0.f;
    }
  }
}

// ---- bf16 MFMA GEMM: C[M][N] = A[M][K] * Bm[N][K]^T (+bias1+bias2), bf16 out ----
__global__ __launch_bounds__(256) void k_gemm(const short* __restrict__ A, int lda,
    const short* __restrict__ Bm, int ldb, int bcol0,
    short* __restrict__ C, int ldc, int ksteps,
    const float* __restrict__ bias1, const float* __restrict__ bias2) {
  int w = threadIdx.x >> 6, l = threadIdx.x & 63;
  int lc = l & 15, lq = l >> 4;
  int arow = blockIdx.x * 64 + w * 16 + lc;
  f32x4 acc[4];
  const f32x4 z = {0.f, 0.f, 0.f, 0.f};
#pragma unroll
  for (int i = 0; i < 4; i++) acc[i] = z;
  const short* ap = A + (size_t)arow * lda + lq * 8;
  for (int kk = 0; kk < ksteps; ++kk) {
    s16x8 a = *(const s16x8*)(ap + kk * 32);
#pragma unroll
    for (int nt = 0; nt < 4; ++nt) {
      int brow = blockIdx.y * 64 + nt * 16 + lc;
      s16x8 b = *(const s16x8*)(Bm + (size_t)brow * ldb + bcol0 + kk * 32 + lq * 8);
      acc[nt] = __builtin_amdgcn_mfma_f32_16x16x32_bf16(a, b, acc[nt], 0, 0, 0);
    }
  }
#pragma unroll
  for (int nt = 0; nt < 4; ++nt) {
    int col = blockIdx.y * 64 + nt * 16 + lc;
    float badd = (bias1 ? bias1[col] : 0.f) + (bias2 ? bias2[col] : 0.f);
#pragma unroll
    for (int j = 0; j < 4; j++) {
      int r = blockIdx.x * 64 + w * 16 + lq * 4 + j;
      C[(size_t)r * ldc + col] = f2bf(acc[nt][j] + badd);
    }
  }
}

// xproj_t[t][gc][b] = xbase[b][gc] + eproj[tok(b,t)][gc]   (bf16, transposed)
// grid (16 cchunk, 4 g, 64 t), block 256. LDS transpose tile [64c][264 pad] shorts.
__global__ __launch_bounds__(256) void k_xproj_t(const short* __restrict__ xb,
    const short* __restrict__ ep, const int* __restrict__ atruth,
    short* __restrict__ out) {
  __shared__ short tile[64 * 264];
  const int cc = blockIdx.x, g = blockIdx.y, t = blockIdx.z;
  const int b = threadIdx.x;
  const int tok = (t == 0) ? 0 : atruth[b * TT + t - 1];
  const int gc0 = g * 1024 + cc * 64;
  const short* xs = xb + (size_t)b * G4 + gc0;
  const short* es = ep + (size_t)tok * G4 + gc0;
#pragma unroll
  for (int i = 0; i < 64; i += 8) {
    s16x8 xv = *(const s16x8*)(xs + i);
    s16x8 ev = *(const s16x8*)(es + i);
#pragma unroll
    for (int j = 0; j < 8; ++j)
      tile[(i + j) * 264 + b] = f2bf(bf2f((unsigned short)xv[j]) + bf2f((unsigned short)ev[j]));
  }
  __syncthreads();
  const int c = threadIdx.x >> 2, b0 = (threadIdx.x & 3) * 64;
  short* dst = out + ((size_t)t * G4 + gc0 + c) * BB + b0;
  const short* src = tile + c * 264 + b0;
#pragma unroll
  for (int i = 0; i < 64; i += 8) *(s16x8*)(dst + i) = *(const s16x8*)(src + i);
}

// ---- persistent LSTM recurrence ----
// 256 WGs (1/CU), 512 threads. Group = 64 WGs over 64 batch rows (2 XCDs);
// each WG owns 16 hidden cols. Waves: (wy 0..3 row-slab) x (kh 0..1 k-half);
// each wave computes ALL 4 gates for 16 rows x 16 cols over its k-half.
// kh=1 writes f32 partials to LDS; kh=0 adds + activates IN REGISTER.
__global__ __launch_bounds__(512, 2) void k_lstm(const float* __restrict__ Whh,
    const short* __restrict__ xproj, const float* __restrict__ c0,
    char* __restrict__ ws) {
  extern __shared__ char sm[];
  float* part = (float*)(sm + 131072);        // [4 wy][64 lane][20 pad] f32
  const int bid = blockIdx.x;
  const int xcd = bid & 7, slot = bid >> 3;
  const int mg = xcd >> 1;                    // batch group 0..3
  const int hb = slot * 2 + (xcd & 1);        // hidden block 0..63
  const int wgid = (xcd & 1) * 32 + slot;     // id within group 0..63
  const int tid = threadIdx.x;
  const int w = tid >> 6, l = tid & 63;
  const int lc = l & 15, lq = l >> 4;
  const int wy = w & 3, kh = w >> 2;          // row-slab(16) / k-half(512)

  // stage W_hh slice -> LDS bf16 swizzled: row r=g*16+rl at r*2048, byte k ^ ((rl&7)<<4)
  {
    const int r = tid >> 3, q = tid & 7;
    const int g = r >> 4, rl = r & 15;
    const float* src = Whh + (size_t)(g * HH + hb * 16 + rl) * HH + q * 128;
    const int swz = (rl & 7) << 4;
    char* dst = sm + r * 2048;
#pragma unroll
    for (int i = 0; i < 128; i += 8) {
      float4 f0 = *(const float4*)(src + i);
      float4 f1 = *(const float4*)(src + i + 4);
      s16x8 o;
      o[0]=f2bf(f0.x); o[1]=f2bf(f0.y); o[2]=f2bf(f0.z); o[3]=f2bf(f0.w);
      o[4]=f2bf(f1.x); o[5]=f2bf(f1.y); o[6]=f2bf(f1.z); o[7]=f2bf(f1.w);
      int koff = (q * 128 + i) * 2;
      *(s16x8*)(dst + (koff ^ swz)) = o;
    }
  }

  const int colbase = hb * 16;
  short* hs = (short*)(ws + WS_HS);
  int* flags = (int*)(ws + WS_CNT);
  const int swzl = (lc & 7) << 4;
  const int row0 = mg * 64 + wy * 16;         // this wave's batch rows

  // c-state (kh=0 lanes): cell (row0 + lq*4 + j, colbase + lc)
  float cst[4];
  if (kh == 0) {
#pragma unroll
    for (int j = 0; j < 4; ++j)
      cst[j] = c0[(size_t)(row0 + lq * 4 + j) * HH + colbase + lc];
  }
  float* pslot = part + ((size_t)wy * 64 + l) * 20;
  __syncthreads();

  for (int t = 0; t < TT; ++t) {
    // xproj prefetch (kh=0 only): [t][g*1024+colbase+lc][row0+lq*4 .. +3]
    s16x4 xg0, xg1, xg2, xg3;
    if (kh == 0) {
      const short* xp = xproj + ((size_t)t * G4 + colbase + lc) * BB + row0 + lq * 4;
      xg0 = *(const s16x4*)(xp);
      xg1 = *(const s16x4*)(xp + (size_t)1024 * BB);
      xg2 = *(const s16x4*)(xp + (size_t)2048 * BB);
      xg3 = *(const s16x4*)(xp + (size_t)3072 * BB);
    }

    if (t && w == 0) {  // wave-0 poll: all 64 group flags >= t
      const int* f = flags + mg * 64 + l;
      for (;;) {
        int v = load_int_cc(f);
        if (__all(v >= t)) break;
        __builtin_amdgcn_s_sleep(4);
      }
    }
    __syncthreads();

    // MFMA: 4 gates x 16 rows x 16 cols over k-half kh
    const f32x4 z = {0.f, 0.f, 0.f, 0.f};
    f32x4 acc0 = z, acc1 = z, acc2 = z, acc3 = z;
    const short* arowp = hs + (size_t)t * (BB * HH) + (size_t)(row0 + lc) * HH + kh * 512 + lq * 8;
#pragma unroll
    for (int kk = 0; kk < 16; ++kk) {
      s16x8 a = *(const s16x8*)(arowp + kk * 32);
      const int kx = (((kh * 16 + kk) * 64) + lq * 16) ^ swzl;
      const char* bp = sm + lc * 2048 + kx;
      acc0 = __builtin_amdgcn_mfma_f32_16x16x32_bf16(a, *(const s16x8*)(bp), acc0, 0, 0, 0);
      acc1 = __builtin_amdgcn_mfma_f32_16x16x32_bf16(a, *(const s16x8*)(bp + 16 * 2048), acc1, 0, 0, 0);
      acc2 = __builtin_amdgcn_mfma_f32_16x16x32_bf16(a, *(const s16x8*)(bp + 32 * 2048), acc2, 0, 0, 0);
      acc3 = __builtin_amdgcn_mfma_f32_16x16x32_bf16(a, *(const s16x8*)(bp + 48 * 2048), acc3, 0, 0, 0);
    }

    // partial exchange: kh=1 writes, kh=0 reduces (stride 80B -> conflict-free b128)
    if (kh == 1) {
      *(f32x4*)(pslot) = acc0;
      *(f32x4*)(pslot + 4) = acc1;
      *(f32x4*)(pslot + 8) = acc2;
      *(f32x4*)(pslot + 12) = acc3;
    }
    __syncthreads();

    if (kh == 0) {
      acc0 += *(const f32x4*)(pslot);
      acc1 += *(const f32x4*)(pslot + 4);
      acc2 += *(const f32x4*)(pslot + 8);
      acc3 += *(const f32x4*)(pslot + 12);
      short* hrow = hs + (size_t)(t + 1) * (BB * HH) + (size_t)(row0 + lq * 4) * HH + colbase + lc;
#pragma unroll
      for (int j = 0; j < 4; ++j) {
        float pi = acc0[j] + bf2f((unsigned short)xg0[j]);
        float pf = acc1[j] + bf2f((unsigned short)xg1[j]);
        float pg = acc2[j] + bf2f((unsigned short)xg2[j]);
        float po = acc3[j] + bf2f((unsigned short)xg3[j]);
        float cv = fsig(pf) * cst[j] + fsig(pi) * ftanh(pg);
        cst[j] = cv;
        float hv = fsig(po) * ftanh(cv);
        store_short_cc(hrow + (size_t)j * HH, (unsigned)(unsigned short)f2bf(hv));
      }
    }
    asm volatile("s_waitcnt vmcnt(0)" ::: "memory");
    __syncthreads();
    if (tid == 0 && t < TT - 1) store_dword_cc(flags + mg * 64 + wgid, t + 1);
  }
}

// ---- logits + fused log-softmax + masked NLL partial sums ----
__global__ __launch_bounds__(256, 1) void k_logits(const short* __restrict__ hsb,
    const short* __restrict__ Wo, const float* __restrict__ bout,
    const int* __restrict__ atruth, const void* __restrict__ maskp,
    char* __restrict__ ws) {
  extern __shared__ char sm[];
  const int tid = threadIdx.x;
  const int w = tid >> 6, l = tid & 63;
  const int lc = l & 15, lq = l >> 4;
  const int rowbase = blockIdx.x * 64 + w * 16;
  f32x4 acc[32];
#pragma unroll
  for (int nt = 0; nt < 32; ++nt) {
    float bv = bout[nt * 16 + lc];
    f32x4 tmp = {bv, bv, bv, bv};
    acc[nt] = tmp;
  }
  const int swzl = (lc & 7) << 4;
  for (int kb = 0; kb < 16; ++kb) {
    __syncthreads();
    {
      const int r0 = tid >> 3, q = tid & 7;
#pragma unroll
      for (int i = 0; i < 16; i++) {
        int r = r0 + 32 * i;
        s16x8 v = *(const s16x8*)(Wo + (size_t)r * HH + kb * 64 + q * 8);
        *(s16x8*)(sm + r * 128 + ((q * 16) ^ ((r & 7) << 4))) = v;
      }
    }
    __syncthreads();
#pragma unroll
    for (int ks = 0; ks < 2; ++ks) {
      s16x8 a = *(const s16x8*)(hsb + (size_t)(rowbase + lc) * HH + kb * 64 + ks * 32 + lq * 8);
      const int kx = (ks * 64 + lq * 16) ^ swzl;
#pragma unroll
      for (int nt = 0; nt < 32; ++nt) {
        s16x8 b = *(const s16x8*)(sm + (nt * 16 + lc) * 128 + kx);
        acc[nt] = __builtin_amdgcn_mfma_f32_16x16x32_bf16(a, b, acc[nt], 0, 0, 0);
      }
    }
  }
  const int bytemode = ((const int*)(ws + WS_FLAG))[0];
  const unsigned char* mb = (const unsigned char*)maskp;
  const int* mi = (const int*)maskp;
  float nlls = 0.f, cnts = 0.f;
#pragma unroll
  for (int j = 0; j < 4; j++) {
    int gr = rowbase + lq * 4 + j;
    int tt = gr >> 8, b = gr & 255;
    float m = -1e30f;
#pragma unroll
    for (int nt = 0; nt < 32; ++nt) m = fmaxf(m, acc[nt][j]);
    m = fmaxf(m, __shfl_xor(m, 1)); m = fmaxf(m, __shfl_xor(m, 2));
    m = fmaxf(m, __shfl_xor(m, 4)); m = fmaxf(m, __shfl_xor(m, 8));
    float s = 0.f;
#pragma unroll
    for (int nt = 0; nt < 32; ++nt) s += __expf(acc[nt][j] - m);
    s += __shfl_xor(s, 1); s += __shfl_xor(s, 2);
    s += __shfl_xor(s, 4); s += __shfl_xor(s, 8);
    float lse = m + __logf(s);
    int tg = atruth[b * TT + tt];
    int mk = bytemode ? (int)mb[b * TT + tt] : mi[b * TT + tt];
    if (((tg & 15) == lc) && mk) {
      float tl = 0.f;
#pragma unroll
      for (int nt = 0; nt < 32; ++nt) if (nt == (tg >> 4)) tl = acc[nt][j];
      nlls += (lse - tl);
    }
    if (lc == 0 && mk) cnts += 1.f;
  }
#pragma unroll
  for (int off = 1; off < 64; off <<= 1) {
    nlls += __shfl_xor(nlls, off);
    cnts += __shfl_xor(cnts, off);
  }
  if (l == 0) {
    float* accf = (float*)(ws + WS_ACC);
    atomicAdd(&accf[0], nlls);
    atomicAdd(&accf[1], cnts);
  }
}

__global__ void k_final(const char* __restrict__ ws, float* __restrict__ out) {
  const float* accf = (const float*)(ws + WS_ACC);
  out[0] = accf[0] / accf[1];
}

extern "C" void kernel_launch(void* const* d_in, const int* in_sizes, int n_in,
                              void* d_out, int out_size, void* d_ws, size_t ws_size,
                              hipStream_t stream) {
  const float* x      = (const float*)d_in[0];
  const int*   atruth = (const int*)d_in[1];
  const void*  amask  = d_in[2];
  const float* emb    = (const float*)d_in[3];
  const float* W_ih   = (const float*)d_in[4];
  const float* W_hh   = (const float*)d_in[5];
  const float* b_ih   = (const float*)d_in[6];
  const float* b_hh   = (const float*)d_in[7];
  const float* W_out  = (const float*)d_in[8];
  const float* b_out  = (const float*)d_in[9];
  const float* h0     = (const float*)d_in[10];
  const float* c0     = (const float*)d_in[11];
  char* ws = (char*)d_ws;
  float* out = (float*)d_out;

  hipFuncSetAttribute((const void*)k_lstm, hipFuncAttributeMaxDynamicSharedMemorySize, 151552);
  hipFuncSetAttribute((const void*)k_logits, hipFuncAttributeMaxDynamicSharedMemorySize, 65536);

  k_f2bf8<<<dim3((G4 * DINk / 8 + 255) / 256), 256, 0, stream>>>(W_ih, (short*)(ws + WS_WIH), G4 * DINk / 8);
  k_f2bf8<<<dim3((NTAG * HH / 8 + 255) / 256), 256, 0, stream>>>(W_out, (short*)(ws + WS_WOUT), NTAG * HH / 8);
  k_f2bf8<<<dim3((BB * XD / 8 + 255) / 256), 256, 0, stream>>>(x, (short*)(ws + WS_XBF), BB * XD / 8);
  k_f2bf8<<<dim3((NTAG * CCG / 8 + 255) / 256), 256, 0, stream>>>(emb, (short*)(ws + WS_EMBBF), NTAG * CCG / 8);

  k_init<<<64, 256, 0, stream>>>(h0, (const int*)amask, ws);

  // xbase = x @ W_ih[:, :512]^T + b_ih + b_hh    [256, 4096] bf16
  k_gemm<<<dim3(4, 64), 256, 0, stream>>>((short*)(ws + WS_XBF), XD, (short*)(ws + WS_WIH), DINk, 0,
                                          (short*)(ws + WS_XBASE), G4, XD / 32, b_ih, b_hh);
  // eproj = emb @ W_ih[:, 512:]^T                [512, 4096] bf16
  k_gemm<<<dim3(8, 64), 256, 0, stream>>>((short*)(ws + WS_EMBBF), CCG, (short*)(ws + WS_WIH), DINk, XD,
                                          (short*)(ws + WS_EPROJ), G4, CCG / 32, nullptr, nullptr);

  // xproj_t[t][gc][b] = xbase[b][gc] + eproj[prev_tok][gc]  (bf16 transposed)
  k_xproj_t<<<dim3(16, 4, 64), 256, 0, stream>>>((const short*)(ws + WS_XBASE),
                                                 (const short*)(ws + WS_EPROJ), atruth,
                                                 (short*)(ws + WS_XPROJ));

  k_lstm<<<256, 512, 151552, stream>>>(W_hh, (const short*)(ws + WS_XPROJ), c0, ws);

  k_logits<<<256, 256, 65536, stream>>>((short*)(ws + WS_HS) + BB * HH, (short*)(ws + WS_WOUT), b_out,
                                        atruth, amask, ws);
  k_final<<<1, 1, 0, stream>>>(ws, out);
}